// Round 3
// baseline (409.125 us; speedup 1.0000x reference)
//
#include <hip/hip_runtime.h>
#include <hip/hip_bf16.h>
#include <cstdint>

typedef __attribute__((ext_vector_type(8))) short bf16x8;
typedef __attribute__((ext_vector_type(4))) float f32x4;

#define B_SZ 8192
#define QS 2048          // quarter size
#define TROW 3456        // 27*128 bf16, per-sample stride of T buffer

__device__ __forceinline__ void gld_lds16(const void* g, void* l) {
    __builtin_amdgcn_global_load_lds(
        (const __attribute__((address_space(1))) unsigned int*)g,
        (__attribute__((address_space(3))) unsigned int*)l, 16, 0, 0);
}

// ---------------- role types ----------------
#define RT_GEMM 0
#define RT_EMB  1
#define RT_INT  2
#define RT_FIN  3
#define RT_CVT  4
#define RT_B0   5

struct Role { int type, i0, i1, i2; const void *a, *b, *c; void *d; };
struct Sched { Role r[3]; int start[3]; int nr; };
struct CvtJob { const float* in; __hip_bfloat16* out; int N, K, Kp; };
struct CvtJobs { CvtJob j[6]; int start[7]; };

// ---------------- GEMM 128x128 tile, 4 waves 2x2, relu(A@W^T + bias) ----------------
__device__ __forceinline__ void gemm128_dev(int lb, int tid,
    const __hip_bfloat16* __restrict__ A, const __hip_bfloat16* __restrict__ W,
    const float* __restrict__ bias, __hip_bfloat16* __restrict__ C,
    int N, int K, int ldc, char* smem_) {
    __hip_bfloat16* ABs = (__hip_bfloat16*)smem_;     // 256*32 bf16 = 16KB
    const int lane = tid & 63, wave = tid >> 6;
    const int wmI = wave >> 1, wnI = wave & 1;
    const int nbx = N >> 7;
    const int by = lb / nbx, bx = lb - by * nbx;
    const int m0 = by * 128, n0 = bx * 128;

    const __hip_bfloat16* gp[4];
    #pragma unroll
    for (int c = 0; c < 4; c++) {
        int gid = c * 256 + tid;
        int row = gid >> 2, col = (gid & 3) * 8;
        gp[c] = (row < 128 ? A + (size_t)(m0 + row) * K
                           : W + (size_t)(n0 + row - 128) * K) + col;
    }

    f32x4 acc[4][4] = {};
    const int fr = lane & 15, fkb = (lane >> 4) * 8;

    for (int k0 = 0; k0 < K; k0 += 32) {
        __syncthreads();
        #pragma unroll
        for (int c = 0; c < 4; c++)
            gld_lds16(gp[c] + k0, &ABs[(c * 256 + wave * 64) * 8]);
        asm volatile("s_waitcnt vmcnt(0)" ::: "memory");
        __syncthreads();
        bf16x8 a[4], b[4];
        #pragma unroll
        for (int i = 0; i < 4; i++)
            a[i] = *(const bf16x8*)&ABs[(wmI * 64 + i * 16 + fr) * 32 + fkb];
        #pragma unroll
        for (int j = 0; j < 4; j++)
            b[j] = *(const bf16x8*)&ABs[(128 + wnI * 64 + j * 16 + fr) * 32 + fkb];
        #pragma unroll
        for (int i = 0; i < 4; i++)
            #pragma unroll
            for (int j = 0; j < 4; j++)
                acc[i][j] = __builtin_amdgcn_mfma_f32_16x16x32_bf16(a[i], b[j], acc[i][j], 0, 0, 0);
    }

    const int fq = lane >> 4;
    #pragma unroll
    for (int i = 0; i < 4; i++)
        #pragma unroll
        for (int j = 0; j < 4; j++) {
            int n = n0 + wnI * 64 + j * 16 + fr;
            float bv = bias[n];
            #pragma unroll
            for (int r = 0; r < 4; r++) {
                int m = m0 + wmI * 64 + i * 16 + fq * 4 + r;
                C[(size_t)m * ldc + n] = __float2bfloat16(fmaxf(acc[i][j][r] + bv, 0.f));
            }
        }
}

// ---------------- embedding gather-sum (one quarter, table-major block order) ----------------
__device__ __forceinline__ void emb_dev(int lb, int tid, int q0,
    const int* __restrict__ idx, const float* __restrict__ tab,
    __hip_bfloat16* __restrict__ T) {
    int lane = tid & 63, wv = tid >> 6;
    int p = lb * 4 + wv;          // p in [0, 26*QS)
    int t = p >> 11;              // table (QS = 2048)
    int b = q0 + (p & (QS - 1));
    const int* ip = idx + (size_t)t * 81920 + b * 10;
    const float* tb = tab + (size_t)t * 100000 * 128;
    float ax = 0.f, ay = 0.f;
    #pragma unroll
    for (int j = 0; j < 10; j++) {
        int r = ip[j];
        float2 v = ((const float2*)(tb + (size_t)r * 128))[lane];
        ax += v.x; ay += v.y;
    }
    __hip_bfloat162 o;
    o.x = __float2bfloat16(ax);
    o.y = __float2bfloat16(ay);
    ((__hip_bfloat162*)(T + (size_t)b * TROW + (1 + t) * 128))[lane] = o;
}

// ---------------- interaction: 4 samples/block, 32x32 Gram ----------------
__device__ __forceinline__ void interact_dev(int lb, int tid, int q0,
    const __hip_bfloat16* __restrict__ T, __hip_bfloat16* __restrict__ z, char* smem_) {
    int lane = tid & 63, wave = tid >> 6;
    int b = q0 + lb * 4 + wave;
    __hip_bfloat16* Sw = (__hip_bfloat16*)(smem_ + wave * 8192);
    const uint4* src = (const uint4*)(T + (size_t)b * TROW);
    uint4* dst = (uint4*)Sw;
    for (int i = lane; i < 432; i += 64) dst[i] = src[i];
    uint4 z4 = {0u, 0u, 0u, 0u};
    for (int i = 432 + lane; i < 512; i += 64) dst[i] = z4;
    __syncthreads();

    const int fr = lane & 15, fkb = (lane >> 4) * 8;
    bf16x8 fr2[2][4];
    #pragma unroll
    for (int mi = 0; mi < 2; mi++)
        #pragma unroll
        for (int kt = 0; kt < 4; kt++)
            fr2[mi][kt] = *(const bf16x8*)&Sw[(mi * 16 + fr) * 128 + kt * 32 + fkb];

    f32x4 acc[2][2] = {};
    #pragma unroll
    for (int kt = 0; kt < 4; kt++)
        #pragma unroll
        for (int mi = 0; mi < 2; mi++)
            #pragma unroll
            for (int ni = 0; ni < 2; ni++)
                acc[mi][ni] = __builtin_amdgcn_mfma_f32_16x16x32_bf16(fr2[mi][kt], fr2[ni][kt], acc[mi][ni], 0, 0, 0);

    __hip_bfloat16* zb = z + (size_t)b * 512;
    zb[lane] = Sw[lane];
    zb[64 + lane] = Sw[64 + lane];
    if (lane < 33) zb[479 + lane] = __float2bfloat16(0.f);
    const int fq = lane >> 4;
    #pragma unroll
    for (int mi = 0; mi < 2; mi++)
        #pragma unroll
        for (int ni = 0; ni < 2; ni++)
            #pragma unroll
            for (int r = 0; r < 4; r++) {
                int m = mi * 16 + fq * 4 + r;
                int n = ni * 16 + fr;
                if (m < 27 && n < 27 && m < n) {
                    int p = m * 26 - (m * (m - 1)) / 2 + (n - m - 1);
                    zb[128 + p] = __float2bfloat16(acc[mi][ni][r]);
                }
            }
}

// ---------------- final dot + sigmoid ----------------
__device__ __forceinline__ void final_dev(int lb, int tid, int q0,
    const __hip_bfloat16* __restrict__ h, const float* __restrict__ w,
    const float* __restrict__ bias, float* __restrict__ out_) {
    int lane = tid & 63, wv = tid >> 6;
    int s = q0 + lb * 4 + wv;
    const __hip_bfloat16* hp = h + (size_t)s * 256;
    float sum = 0.f;
    #pragma unroll
    for (int i = 0; i < 4; i++) {
        int k = i * 64 + lane;
        sum += __bfloat162float(hp[k]) * w[k];
    }
    #pragma unroll
    for (int off = 32; off; off >>= 1) sum += __shfl_down(sum, off, 64);
    if (lane == 0) out_[s] = 1.f / (1.f + expf(-(sum + bias[0])));
}

// ---------------- batched weight convert fp32 -> bf16 (K-padded) ----------------
__device__ __forceinline__ void cvt_dev(int lb, int tid, const CvtJobs& J) {
    int gid = lb * 256 + tid;
    if (gid >= J.start[6]) return;
    int k = 0;
    #pragma unroll
    for (int i = 1; i < 6; i++) if (gid >= J.start[i]) k = i;
    const CvtJob& job = J.j[k];
    int local = gid - J.start[k];
    int n = local / job.Kp, kk = local - n * job.Kp;
    float v = (kk < job.K) ? job.in[(size_t)n * job.K + kk] : 0.f;
    job.out[local] = __float2bfloat16(v);
}

// ---------------- bottom layer 0 in fp32 (K=13, no cvt needed) ----------------
__device__ __forceinline__ void bot0_dev(int lb, int tid, const float* __restrict__ x,
    const float* __restrict__ w, const float* __restrict__ bias,
    __hip_bfloat16* __restrict__ o, char* smem_) {
    float* xs = (float*)smem_;       // 52 floats: rows m0..m0+3 x 13 (contiguous in x)
    int m0 = lb * 4;
    if (tid < 52) xs[tid] = x[(size_t)m0 * 13 + tid];
    __syncthreads();
    for (int c = tid; c < 512; c += 256) {
        const float* wr = w + (size_t)c * 13;
        float bv = bias[c];
        #pragma unroll
        for (int r = 0; r < 4; r++) {
            float s = bv;
            #pragma unroll
            for (int k = 0; k < 13; k++) s += xs[r * 13 + k] * wr[k];
            o[(size_t)(m0 + r) * 512 + c] = __float2bfloat16(fmaxf(s, 0.f));
        }
    }
}

// ---------------- fused role-dispatch kernel ----------------
__global__ __launch_bounds__(256) void fused_kernel(Sched S, CvtJobs J) {
    __shared__ __align__(16) char smem[32768];
    int blk = blockIdx.x;
    int ri = 0;
    if (S.nr > 1 && blk >= S.start[1]) ri = 1;
    if (S.nr > 2 && blk >= S.start[2]) ri = 2;
    const Role& R = S.r[ri];
    int lb = blk - S.start[ri];
    int tid = threadIdx.x;
    switch (R.type) {
        case RT_GEMM:
            gemm128_dev(lb, tid, (const __hip_bfloat16*)R.a, (const __hip_bfloat16*)R.b,
                        (const float*)R.c, (__hip_bfloat16*)R.d, R.i0, R.i1, R.i2, smem);
            break;
        case RT_EMB:
            emb_dev(lb, tid, R.i0, (const int*)R.a, (const float*)R.b, (__hip_bfloat16*)R.d);
            break;
        case RT_INT:
            interact_dev(lb, tid, R.i0, (const __hip_bfloat16*)R.a, (__hip_bfloat16*)R.d, smem);
            break;
        case RT_FIN:
            final_dev(lb, tid, R.i0, (const __hip_bfloat16*)R.a, (const float*)R.b,
                      (const float*)R.c, (float*)R.d);
            break;
        case RT_CVT:
            cvt_dev(lb, tid, J);
            break;
        case RT_B0:
            bot0_dev(lb, tid, (const float*)R.a, (const float*)R.b, (const float*)R.c,
                     (__hip_bfloat16*)R.d, smem);
            break;
    }
}

extern "C" void kernel_launch(void* const* d_in, const int* in_sizes, int n_in,
                              void* d_out, int out_size, void* d_ws, size_t ws_size,
                              hipStream_t stream) {
    const float* dense_x = (const float*)d_in[0];
    const int* sidx      = (const int*)d_in[1];
    const float* emb     = (const float*)d_in[2];
    const float* bw0 = (const float*)d_in[3];  const float* bb0 = (const float*)d_in[4];
    const float* bw1 = (const float*)d_in[5];  const float* bb1 = (const float*)d_in[6];
    const float* bw2 = (const float*)d_in[7];  const float* bb2 = (const float*)d_in[8];
    const float* tw0 = (const float*)d_in[9];  const float* tb0 = (const float*)d_in[10];
    const float* tw1 = (const float*)d_in[11]; const float* tb1 = (const float*)d_in[12];
    const float* tw2 = (const float*)d_in[13]; const float* tb2 = (const float*)d_in[14];
    const float* tw3 = (const float*)d_in[15]; const float* tb3 = (const float*)d_in[16];
    const float* tw4 = (const float*)d_in[17]; const float* tb4 = (const float*)d_in[18];
    float* out = (float*)d_out;

    char* ws = (char*)d_ws;
    size_t off = 0;
    auto alloc = [&](size_t bytes) {
        off = (off + 255) & ~(size_t)255;
        void* p = ws + off;
        off += bytes;
        return p;
    };
    __hip_bfloat16* Wb1 = (__hip_bfloat16*)alloc((size_t)256 * 512 * 2);
    __hip_bfloat16* Wb2 = (__hip_bfloat16*)alloc((size_t)128 * 256 * 2);
    __hip_bfloat16* Wt0 = (__hip_bfloat16*)alloc((size_t)1024 * 512 * 2);
    __hip_bfloat16* Wt1 = (__hip_bfloat16*)alloc((size_t)1024 * 1024 * 2);
    __hip_bfloat16* Wt2 = (__hip_bfloat16*)alloc((size_t)512 * 1024 * 2);
    __hip_bfloat16* Wt3 = (__hip_bfloat16*)alloc((size_t)256 * 512 * 2);
    __hip_bfloat16* bufA = (__hip_bfloat16*)alloc((size_t)B_SZ * 512 * 2);
    __hip_bfloat16* bufB = (__hip_bfloat16*)alloc((size_t)B_SZ * 256 * 2);
    __hip_bfloat16* Tbuf = (__hip_bfloat16*)alloc((size_t)B_SZ * TROW * 2);
    __hip_bfloat16* zbuf = (__hip_bfloat16*)alloc((size_t)B_SZ * 512 * 2);
    __hip_bfloat16* h0   = (__hip_bfloat16*)alloc((size_t)B_SZ * 1024 * 2);
    __hip_bfloat16* h1   = (__hip_bfloat16*)alloc((size_t)B_SZ * 1024 * 2);
    __hip_bfloat16* h2   = (__hip_bfloat16*)alloc((size_t)B_SZ * 512 * 2);
    __hip_bfloat16* h3   = (__hip_bfloat16*)alloc((size_t)B_SZ * 256 * 2);

    // weight conversion jobs (bot0 consumed in fp32 directly — no cvt)
    CvtJobs J;
    auto setJob = [&](int i, const float* in, __hip_bfloat16* o, int N, int K, int Kp) {
        J.j[i] = {in, o, N, K, Kp};
    };
    setJob(0, bw1, Wb1, 256, 512, 512);
    setJob(1, bw2, Wb2, 128, 256, 256);
    setJob(2, tw0, Wt0, 1024, 479, 512);
    setJob(3, tw1, Wt1, 1024, 1024, 1024);
    setJob(4, tw2, Wt2, 512, 1024, 1024);
    setJob(5, tw3, Wt3, 256, 512, 512);
    J.start[0] = 0;
    for (int i = 0; i < 6; i++) J.start[i + 1] = J.start[i] + J.j[i].N * J.j[i].Kp;
    const int cvtBlocks = (J.start[6] + 255) / 256;
    const int EMB_BLK = 26 * QS / 4;     // 13312 blocks per quarter

    Sched S{};
    int nr = 0, tot = 0;
    auto add = [&](int type, int nblk, const void* a, const void* b, const void* c, void* d,
                   int i0, int i1, int i2) {
        S.r[nr] = {type, i0, i1, i2, a, b, c, d};
        S.start[nr] = tot;
        tot += nblk;
        nr++;
    };
    auto fire = [&]() {
        S.nr = nr;
        fused_kernel<<<tot, 256, 0, stream>>>(S, J);
        S = Sched{}; nr = 0; tot = 0;
    };

    // L1: bot0 (fp32 direct) || weight cvt || emb(Q1)
    add(RT_B0, B_SZ / 4, dense_x, bw0, bb0, bufA, 0, 0, 0);
    add(RT_CVT, cvtBlocks, nullptr, nullptr, nullptr, nullptr, 0, 0, 0);
    add(RT_EMB, EMB_BLK, sidx, emb, nullptr, Tbuf, 0, 0, 0);
    fire();
    // L2: bot1 || emb(Q2)
    add(RT_GEMM, (B_SZ / 128) * (256 / 128), bufA, Wb1, bb1, bufB, 256, 512, 256);
    add(RT_EMB, EMB_BLK, sidx, emb, nullptr, Tbuf, QS, 0, 0);
    fire();
    // L3: bot2 (-> Tbuf row 0) || emb(Q3)
    add(RT_GEMM, (B_SZ / 128) * (128 / 128), bufB, Wb2, bb2, Tbuf, 128, 256, TROW);
    add(RT_EMB, EMB_BLK, sidx, emb, nullptr, Tbuf, 2 * QS, 0, 0);
    fire();
    // L4: interact(samples 0..6144) || emb(Q4)
    add(RT_INT, 3 * QS / 4, Tbuf, nullptr, nullptr, zbuf, 0, 0, 0);
    add(RT_EMB, EMB_BLK, sidx, emb, nullptr, Tbuf, 3 * QS, 0, 0);
    fire();
    // L5: top0(0:6144) || interact(6144:8192)
    add(RT_GEMM, 48 * 8, zbuf, Wt0, tb0, h0, 1024, 512, 1024);
    add(RT_INT, QS / 4, Tbuf, nullptr, nullptr, zbuf, 3 * QS, 0, 0);
    fire();
    // L6: top1(0:6144) || top0(6144:8192)
    add(RT_GEMM, 48 * 8, h0, Wt1, tb1, h1, 1024, 1024, 1024);
    add(RT_GEMM, 16 * 8, zbuf + (size_t)6144 * 512, Wt0, tb0, h0 + (size_t)6144 * 1024, 1024, 512, 1024);
    fire();
    // L7: top2(0:6144) || top1(6144:8192)
    add(RT_GEMM, 48 * 4, h1, Wt2, tb2, h2, 512, 1024, 512);
    add(RT_GEMM, 16 * 8, h0 + (size_t)6144 * 1024, Wt1, tb1, h1 + (size_t)6144 * 1024, 1024, 1024, 1024);
    fire();
    // L8: top3(0:6144) || top2(6144:8192)
    add(RT_GEMM, 48 * 2, h2, Wt3, tb3, h3, 256, 512, 256);
    add(RT_GEMM, 16 * 4, h1 + (size_t)6144 * 1024, Wt2, tb2, h2 + (size_t)6144 * 512, 512, 1024, 512);
    fire();
    // L9: final(0:6144) || top3(6144:8192)
    add(RT_FIN, 3 * QS / 4, h3, tw4, tb4, out, 0, 0, 0);
    add(RT_GEMM, 16 * 2, h2 + (size_t)6144 * 512, Wt3, tb3, h3 + (size_t)6144 * 256, 256, 512, 256);
    fire();
    // L10: final(6144:8192)
    add(RT_FIN, QS / 4, h3, tw4, tb4, out, 3 * QS, 0, 0);
    fire();
}

// Round 4
// 372.128 us; speedup vs baseline: 1.0994x; 1.0994x over previous
//
#include <hip/hip_runtime.h>
#include <hip/hip_bf16.h>
#include <cstdint>

typedef __attribute__((ext_vector_type(8))) short bf16x8;
typedef __attribute__((ext_vector_type(4))) float f32x4;

#define B_SZ 8192
#define MH 4096          // batch half
#define TROW 3456        // 27*128 bf16, per-sample stride of T buffer

__device__ __forceinline__ void gld_lds16(const void* g, void* l) {
    __builtin_amdgcn_global_load_lds(
        (const __attribute__((address_space(1))) unsigned int*)g,
        (__attribute__((address_space(3))) unsigned int*)l, 16, 0, 0);
}

struct GemmD { const __hip_bfloat16 *A, *W; const float* bias; __hip_bfloat16* C; int N, K, ldc; };
struct CvtJob { const float* in; __hip_bfloat16* out; int N, K, Kp; };
struct CvtJobs { CvtJob j[6]; int start[7]; };

// ---------------- GEMM 128x128 tile, 4 waves 2x2, relu(A@W^T + bias) ----------------
__device__ __forceinline__ void gemm128_dev(const GemmD& g, int lb, int tid, char* smem_) {
    __hip_bfloat16* ABs = (__hip_bfloat16*)smem_;     // 16KB
    const int lane = tid & 63, wave = tid >> 6;
    const int wmI = wave >> 1, wnI = wave & 1;
    const int nbx = g.N >> 7;
    const int by = lb / nbx, bx = lb - by * nbx;
    const int m0 = by * 128, n0 = bx * 128;
    const int K = g.K;

    const __hip_bfloat16* gp[4];
    #pragma unroll
    for (int c = 0; c < 4; c++) {
        int gid = c * 256 + tid;
        int row = gid >> 2, col = (gid & 3) * 8;
        gp[c] = (row < 128 ? g.A + (size_t)(m0 + row) * K
                           : g.W + (size_t)(n0 + row - 128) * K) + col;
    }

    f32x4 acc[4][4] = {};
    const int fr = lane & 15, fkb = (lane >> 4) * 8;

    for (int k0 = 0; k0 < K; k0 += 32) {
        __syncthreads();
        #pragma unroll
        for (int c = 0; c < 4; c++)
            gld_lds16(gp[c] + k0, &ABs[(c * 256 + wave * 64) * 8]);
        asm volatile("s_waitcnt vmcnt(0)" ::: "memory");
        __syncthreads();
        bf16x8 a[4], b[4];
        #pragma unroll
        for (int i = 0; i < 4; i++)
            a[i] = *(const bf16x8*)&ABs[(wmI * 64 + i * 16 + fr) * 32 + fkb];
        #pragma unroll
        for (int j = 0; j < 4; j++)
            b[j] = *(const bf16x8*)&ABs[(128 + wnI * 64 + j * 16 + fr) * 32 + fkb];
        #pragma unroll
        for (int i = 0; i < 4; i++)
            #pragma unroll
            for (int j = 0; j < 4; j++)
                acc[i][j] = __builtin_amdgcn_mfma_f32_16x16x32_bf16(a[i], b[j], acc[i][j], 0, 0, 0);
    }

    const int fq = lane >> 4;
    #pragma unroll
    for (int i = 0; i < 4; i++)
        #pragma unroll
        for (int j = 0; j < 4; j++) {
            int n = n0 + wnI * 64 + j * 16 + fr;
            float bv = g.bias[n];
            #pragma unroll
            for (int r = 0; r < 4; r++) {
                int m = m0 + wmI * 64 + i * 16 + fq * 4 + r;
                g.C[(size_t)m * g.ldc + n] = __float2bfloat16(fmaxf(acc[i][j][r] + bv, 0.f));
            }
        }
}

// ---------------- embedding gather-sum over table slice [t0, t0+nt), full batch ----------------
__device__ __forceinline__ void emb_dev(int lb, int tid, int t0,
    const int* __restrict__ idx, const float* __restrict__ tab,
    __hip_bfloat16* __restrict__ T) {
    int lane = tid & 63, wv = tid >> 6;
    int p = lb * 4 + wv;
    int t = t0 + (p >> 13);       // 8192 samples per table
    int b = p & 8191;
    const int* ip = idx + (size_t)t * 81920 + b * 10;
    const float* tb = tab + (size_t)t * 100000 * 128;
    float ax = 0.f, ay = 0.f;
    #pragma unroll
    for (int j = 0; j < 10; j++) {
        int r = ip[j];
        float2 v = ((const float2*)(tb + (size_t)r * 128))[lane];
        ax += v.x; ay += v.y;
    }
    __hip_bfloat162 o;
    o.x = __float2bfloat16(ax);
    o.y = __float2bfloat16(ay);
    ((__hip_bfloat162*)(T + (size_t)b * TROW + (1 + t) * 128))[lane] = o;
}

// ---------------- interaction: 4 samples/block, 32x32 Gram ----------------
__device__ __forceinline__ void interact_dev(int lb, int tid, int s0,
    const __hip_bfloat16* __restrict__ T, __hip_bfloat16* __restrict__ z, char* smem_) {
    int lane = tid & 63, wave = tid >> 6;
    int b = s0 + lb * 4 + wave;
    __hip_bfloat16* Sw = (__hip_bfloat16*)(smem_ + wave * 8192);
    const uint4* src = (const uint4*)(T + (size_t)b * TROW);
    uint4* dst = (uint4*)Sw;
    for (int i = lane; i < 432; i += 64) dst[i] = src[i];
    uint4 z4 = {0u, 0u, 0u, 0u};
    for (int i = 432 + lane; i < 512; i += 64) dst[i] = z4;
    __syncthreads();

    const int fr = lane & 15, fkb = (lane >> 4) * 8;
    bf16x8 fr2[2][4];
    #pragma unroll
    for (int mi = 0; mi < 2; mi++)
        #pragma unroll
        for (int kt = 0; kt < 4; kt++)
            fr2[mi][kt] = *(const bf16x8*)&Sw[(mi * 16 + fr) * 128 + kt * 32 + fkb];

    f32x4 acc[2][2] = {};
    #pragma unroll
    for (int kt = 0; kt < 4; kt++)
        #pragma unroll
        for (int mi = 0; mi < 2; mi++)
            #pragma unroll
            for (int ni = 0; ni < 2; ni++)
                acc[mi][ni] = __builtin_amdgcn_mfma_f32_16x16x32_bf16(fr2[mi][kt], fr2[ni][kt], acc[mi][ni], 0, 0, 0);

    __hip_bfloat16* zb = z + (size_t)b * 512;
    zb[lane] = Sw[lane];
    zb[64 + lane] = Sw[64 + lane];
    if (lane < 33) zb[479 + lane] = __float2bfloat16(0.f);
    const int fq = lane >> 4;
    #pragma unroll
    for (int mi = 0; mi < 2; mi++)
        #pragma unroll
        for (int ni = 0; ni < 2; ni++)
            #pragma unroll
            for (int r = 0; r < 4; r++) {
                int m = mi * 16 + fq * 4 + r;
                int n = ni * 16 + fr;
                if (m < 27 && n < 27 && m < n) {
                    int p = m * 26 - (m * (m - 1)) / 2 + (n - m - 1);
                    zb[128 + p] = __float2bfloat16(acc[mi][ni][r]);
                }
            }
}

// ---------------- final dot + sigmoid ----------------
__device__ __forceinline__ void final_dev(int lb, int tid, int s0,
    const __hip_bfloat16* __restrict__ h, const float* __restrict__ w,
    const float* __restrict__ bias, float* __restrict__ out_) {
    int lane = tid & 63, wv = tid >> 6;
    int s = s0 + lb * 4 + wv;
    const __hip_bfloat16* hp = h + (size_t)s * 256;
    float sum = 0.f;
    #pragma unroll
    for (int i = 0; i < 4; i++) {
        int k = i * 64 + lane;
        sum += __bfloat162float(hp[k]) * w[k];
    }
    #pragma unroll
    for (int off = 32; off; off >>= 1) sum += __shfl_down(sum, off, 64);
    if (lane == 0) out_[s] = 1.f / (1.f + expf(-(sum + bias[0])));
}

// ---------------- batched weight convert fp32 -> bf16 (K-padded) ----------------
__device__ __forceinline__ void cvt_dev(int lb, int tid, const CvtJobs& J) {
    int gid = lb * 256 + tid;
    if (gid >= J.start[6]) return;
    int k = 0;
    #pragma unroll
    for (int i = 1; i < 6; i++) if (gid >= J.start[i]) k = i;
    const CvtJob& job = J.j[k];
    int local = gid - J.start[k];
    int n = local / job.Kp, kk = local - n * job.Kp;
    float v = (kk < job.K) ? job.in[(size_t)n * job.K + kk] : 0.f;
    job.out[local] = __float2bfloat16(v);
}

// ---------------- bottom layer 0 in fp32 (K=13) ----------------
__device__ __forceinline__ void bot0_dev(int lb, int tid, const float* __restrict__ x,
    const float* __restrict__ w, const float* __restrict__ bias,
    __hip_bfloat16* __restrict__ o, char* smem_) {
    float* xs = (float*)smem_;       // 52 floats
    int m0 = lb * 4;
    if (tid < 52) xs[tid] = x[(size_t)m0 * 13 + tid];
    __syncthreads();
    for (int c = tid; c < 512; c += 256) {
        const float* wr = w + (size_t)c * 13;
        float bv = bias[c];
        #pragma unroll
        for (int r = 0; r < 4; r++) {
            float s = bv;
            #pragma unroll
            for (int k = 0; k < 13; k++) s += xs[r * 13 + k] * wr[k];
            o[(size_t)(m0 + r) * 512 + c] = __float2bfloat16(fmaxf(s, 0.f));
        }
    }
}

// ================= launch-specific fused kernels (tight per-launch resources) =================

// L1: cvt || bot0 || emb(tables t0..t0+nt)
__global__ __launch_bounds__(256) void k_l1(CvtJobs J, int cvtB,
    const float* dx, const float* w0, const float* b0, __hip_bfloat16* bufA,
    int t0, const int* sidx, const float* emb, __hip_bfloat16* T) {
    __shared__ __align__(16) char smem[512];
    int blk = blockIdx.x, tid = threadIdx.x;
    if (blk < cvtB) { cvt_dev(blk, tid, J); return; }
    blk -= cvtB;
    if (blk < B_SZ / 4) { bot0_dev(blk, tid, dx, w0, b0, bufA, smem); return; }
    blk -= B_SZ / 4;
    emb_dev(blk, tid, t0, sidx, emb, T);
}

// L2/L3: gemm || emb(tables)
__global__ __launch_bounds__(256) void k_gemm_emb(GemmD g, int gB,
    int t0, const int* sidx, const float* emb, __hip_bfloat16* T) {
    __shared__ __align__(16) char smem[16384];
    if (blockIdx.x < gB) gemm128_dev(g, blockIdx.x, threadIdx.x, smem);
    else emb_dev(blockIdx.x - gB, threadIdx.x, t0, sidx, emb, T);
}

// plain interact
__global__ __launch_bounds__(256) void k_int(const __hip_bfloat16* T, __hip_bfloat16* z, int s0) {
    __shared__ __align__(16) char smem[32768];
    interact_dev(blockIdx.x, threadIdx.x, s0, T, z, smem);
}

// gemm || interact
__global__ __launch_bounds__(256) void k_gemm_int(GemmD g, int gB,
    const __hip_bfloat16* T, __hip_bfloat16* z, int s0) {
    __shared__ __align__(16) char smem[32768];
    if (blockIdx.x < gB) gemm128_dev(g, blockIdx.x, threadIdx.x, smem);
    else interact_dev(blockIdx.x - gB, threadIdx.x, s0, T, z, smem);
}

// gemm || gemm
__global__ __launch_bounds__(256) void k_gemm2(GemmD g0, int b0, GemmD g1) {
    __shared__ __align__(16) char smem[16384];
    if (blockIdx.x < b0) gemm128_dev(g0, blockIdx.x, threadIdx.x, smem);
    else gemm128_dev(g1, blockIdx.x - b0, threadIdx.x, smem);
}

// gemm || final
__global__ __launch_bounds__(256) void k_gemm_fin(GemmD g, int gB,
    const __hip_bfloat16* h, const float* w, const float* bias, float* out_, int s0) {
    __shared__ __align__(16) char smem[16384];
    if (blockIdx.x < gB) gemm128_dev(g, blockIdx.x, threadIdx.x, smem);
    else final_dev(blockIdx.x - gB, threadIdx.x, s0, h, w, bias, out_);
}

// plain final
__global__ __launch_bounds__(256) void k_fin(const __hip_bfloat16* h, const float* w,
                                             const float* bias, float* out_, int s0) {
    final_dev(blockIdx.x, threadIdx.x, s0, h, w, bias, out_);
}

extern "C" void kernel_launch(void* const* d_in, const int* in_sizes, int n_in,
                              void* d_out, int out_size, void* d_ws, size_t ws_size,
                              hipStream_t stream) {
    const float* dense_x = (const float*)d_in[0];
    const int* sidx      = (const int*)d_in[1];
    const float* emb     = (const float*)d_in[2];
    const float* bw0 = (const float*)d_in[3];  const float* bb0 = (const float*)d_in[4];
    const float* bw1 = (const float*)d_in[5];  const float* bb1 = (const float*)d_in[6];
    const float* bw2 = (const float*)d_in[7];  const float* bb2 = (const float*)d_in[8];
    const float* tw0 = (const float*)d_in[9];  const float* tb0 = (const float*)d_in[10];
    const float* tw1 = (const float*)d_in[11]; const float* tb1 = (const float*)d_in[12];
    const float* tw2 = (const float*)d_in[13]; const float* tb2 = (const float*)d_in[14];
    const float* tw3 = (const float*)d_in[15]; const float* tb3 = (const float*)d_in[16];
    const float* tw4 = (const float*)d_in[17]; const float* tb4 = (const float*)d_in[18];
    float* out = (float*)d_out;

    char* ws = (char*)d_ws;
    size_t off = 0;
    auto alloc = [&](size_t bytes) {
        off = (off + 255) & ~(size_t)255;
        void* p = ws + off;
        off += bytes;
        return p;
    };
    __hip_bfloat16* Wb1 = (__hip_bfloat16*)alloc((size_t)256 * 512 * 2);
    __hip_bfloat16* Wb2 = (__hip_bfloat16*)alloc((size_t)128 * 256 * 2);
    __hip_bfloat16* Wt0 = (__hip_bfloat16*)alloc((size_t)1024 * 512 * 2);
    __hip_bfloat16* Wt1 = (__hip_bfloat16*)alloc((size_t)1024 * 1024 * 2);
    __hip_bfloat16* Wt2 = (__hip_bfloat16*)alloc((size_t)512 * 1024 * 2);
    __hip_bfloat16* Wt3 = (__hip_bfloat16*)alloc((size_t)256 * 512 * 2);
    __hip_bfloat16* bufA = (__hip_bfloat16*)alloc((size_t)B_SZ * 512 * 2);
    __hip_bfloat16* bufB = (__hip_bfloat16*)alloc((size_t)B_SZ * 256 * 2);
    __hip_bfloat16* Tbuf = (__hip_bfloat16*)alloc((size_t)B_SZ * TROW * 2);
    __hip_bfloat16* zbuf = (__hip_bfloat16*)alloc((size_t)B_SZ * 512 * 2);
    __hip_bfloat16* h0   = (__hip_bfloat16*)alloc((size_t)B_SZ * 1024 * 2);
    __hip_bfloat16* h1   = (__hip_bfloat16*)alloc((size_t)B_SZ * 1024 * 2);
    __hip_bfloat16* h2   = (__hip_bfloat16*)alloc((size_t)B_SZ * 512 * 2);
    __hip_bfloat16* h3   = (__hip_bfloat16*)alloc((size_t)B_SZ * 256 * 2);

    CvtJobs J;
    auto setJob = [&](int i, const float* in, __hip_bfloat16* o, int N, int K, int Kp) {
        J.j[i] = {in, o, N, K, Kp};
    };
    setJob(0, bw1, Wb1, 256, 512, 512);
    setJob(1, bw2, Wb2, 128, 256, 256);
    setJob(2, tw0, Wt0, 1024, 479, 512);
    setJob(3, tw1, Wt1, 1024, 1024, 1024);
    setJob(4, tw2, Wt2, 512, 1024, 1024);
    setJob(5, tw3, Wt3, 256, 512, 512);
    J.start[0] = 0;
    for (int i = 0; i < 6; i++) J.start[i + 1] = J.start[i] + J.j[i].N * J.j[i].Kp;
    const int cvtB = (J.start[6] + 255) / 256;

    auto embBlk = [](int nt) { return nt * B_SZ / 4; };

    // L1: cvt || bot0 || emb(tables 0..8)
    k_l1<<<cvtB + B_SZ / 4 + embBlk(9), 256, 0, stream>>>(
        J, cvtB, dense_x, bw0, bb0, bufA, 0, sidx, emb, Tbuf);

    // L2: bot1 || emb(tables 9..16)
    {
        GemmD g{bufA, Wb1, bb1, bufB, 256, 512, 256};
        int gB = (B_SZ / 128) * (256 / 128);
        k_gemm_emb<<<gB + embBlk(8), 256, 0, stream>>>(g, gB, 9, sidx, emb, Tbuf);
    }
    // L3: bot2 (-> Tbuf row 0) || emb(tables 17..25)
    {
        GemmD g{bufB, Wb2, bb2, Tbuf, 128, 256, TROW};
        int gB = (B_SZ / 128) * (128 / 128);
        k_gemm_emb<<<gB + embBlk(9), 256, 0, stream>>>(g, gB, 17, sidx, emb, Tbuf);
    }
    // L4: interact(H1)
    k_int<<<MH / 4, 256, 0, stream>>>(Tbuf, zbuf, 0);

    // L5: top0(H1) || interact(H2)
    {
        GemmD g{zbuf, Wt0, tb0, h0, 1024, 512, 1024};
        int gB = (MH / 128) * (1024 / 128);
        k_gemm_int<<<gB + MH / 4, 256, 0, stream>>>(g, gB, Tbuf, zbuf, MH);
    }
    // L6: top1(H1) || top0(H2)
    {
        GemmD g0{h0, Wt1, tb1, h1, 1024, 1024, 1024};
        GemmD g1{zbuf + (size_t)MH * 512, Wt0, tb0, h0 + (size_t)MH * 1024, 1024, 512, 1024};
        int b0 = (MH / 128) * 8, b1 = (MH / 128) * 8;
        k_gemm2<<<b0 + b1, 256, 0, stream>>>(g0, b0, g1);
    }
    // L7: top2(H1) || top1(H2)
    {
        GemmD g0{h1, Wt2, tb2, h2, 512, 1024, 512};
        GemmD g1{h0 + (size_t)MH * 1024, Wt1, tb1, h1 + (size_t)MH * 1024, 1024, 1024, 1024};
        int b0 = (MH / 128) * 4, b1 = (MH / 128) * 8;
        k_gemm2<<<b0 + b1, 256, 0, stream>>>(g0, b0, g1);
    }
    // L8: top3(H1) || top2(H2)
    {
        GemmD g0{h2, Wt3, tb3, h3, 256, 512, 256};
        GemmD g1{h1 + (size_t)MH * 1024, Wt2, tb2, h2 + (size_t)MH * 512, 512, 1024, 512};
        int b0 = (MH / 128) * 2, b1 = (MH / 128) * 4;
        k_gemm2<<<b0 + b1, 256, 0, stream>>>(g0, b0, g1);
    }
    // L9: top3(H2) || final(H1)
    {
        GemmD g{h2 + (size_t)MH * 512, Wt3, tb3, h3 + (size_t)MH * 256, 256, 512, 256};
        int gB = (MH / 128) * 2;
        k_gemm_fin<<<gB + MH / 4, 256, 0, stream>>>(g, gB, h3, tw4, tb4, out, 0);
    }
    // L10: final(H2)
    k_fin<<<MH / 4, 256, 0, stream>>>(h3, tw4, tb4, out, MH);
}

// Round 6
// 326.487 us; speedup vs baseline: 1.2531x; 1.1398x over previous
//
#include <hip/hip_runtime.h>
#include <hip/hip_bf16.h>
#include <cstdint>

typedef __attribute__((ext_vector_type(8))) short bf16x8;
typedef __attribute__((ext_vector_type(4))) float f32x4;

#define B_SZ 8192
#define TROW 3456   // 27*128, per-sample stride of T buffer (bf16 elems)

__device__ __forceinline__ void gld_lds16(const void* g, void* l) {
    __builtin_amdgcn_global_load_lds(
        (const __attribute__((address_space(1))) unsigned int*)g,
        (__attribute__((address_space(3))) unsigned int*)l, 16, 0, 0);
}

__device__ __forceinline__ short f2bf_bits(float v) {
    return __builtin_bit_cast(short, __float2bfloat16(v));
}

// ---------------- pre: vectorized weight cvt (8 elems/thread) || bot0 fp32 ----------------
struct CvtJob { const float* in; __hip_bfloat16* out; int N, K, Kp; };
struct CvtJobs { CvtJob j[6]; int start[7]; };   // starts in ELEMENTS (all sizes %8==0)

__device__ __forceinline__ void cvt_dev8(int lb, int tid, const CvtJobs& J) {
    int chunk = lb * 256 + tid;
    int e = chunk * 8;
    if (e >= J.start[6]) return;
    int k = 0;
    #pragma unroll
    for (int i = 1; i < 6; i++) if (e >= J.start[i]) k = i;
    const CvtJob& job = J.j[k];
    int local = e - J.start[k];
    float v[8];
    if (job.K == job.Kp) {
        const float4* p = (const float4*)(job.in + local);
        float4 a = p[0], b = p[1];
        v[0]=a.x; v[1]=a.y; v[2]=a.z; v[3]=a.w; v[4]=b.x; v[5]=b.y; v[6]=b.z; v[7]=b.w;
    } else {
        int n = local / job.Kp, kk = local - n * job.Kp;
        #pragma unroll
        for (int i = 0; i < 8; i++)
            v[i] = (kk + i < job.K) ? job.in[(size_t)n * job.K + kk + i] : 0.f;
    }
    bf16x8 o;
    #pragma unroll
    for (int i = 0; i < 8; i++)
        o[i] = f2bf_bits(v[i]);
    *(bf16x8*)(job.out + local) = o;
}

__device__ __forceinline__ void bot0_dev(int lb, int tid, const float* __restrict__ x,
    const float* __restrict__ w, const float* __restrict__ bias,
    __hip_bfloat16* __restrict__ o, float* xs) {
    int m0 = lb * 4;
    if (tid < 52) xs[tid] = x[(size_t)m0 * 13 + tid];
    __syncthreads();
    for (int c = tid; c < 512; c += 256) {
        const float* wr = w + (size_t)c * 13;
        float bv = bias[c];
        #pragma unroll
        for (int r = 0; r < 4; r++) {
            float s = bv;
            #pragma unroll
            for (int k = 0; k < 13; k++) s += xs[r * 13 + k] * wr[k];
            o[(size_t)(m0 + r) * 512 + c] = __float2bfloat16(fmaxf(s, 0.f));
        }
    }
}

__global__ __launch_bounds__(256) void k_pre(CvtJobs J, int cvtB,
    const float* dx, const float* w0, const float* b0, __hip_bfloat16* bufA) {
    __shared__ float xs[64];
    int blk = blockIdx.x, tid = threadIdx.x;
    if (blk < cvtB) { cvt_dev8(blk, tid, J); return; }
    bot0_dev(blk - cvtB, tid, dx, w0, b0, bufA, xs);
}

// ---------------- embedding gather-sum (lean, isolated): T[b][1+t][:] = sum_p emb[t][idx][:] ----------------
__global__ __launch_bounds__(256) void emb_kernel(const int* __restrict__ idx,
                                                  const float* __restrict__ tab,
                                                  __hip_bfloat16* __restrict__ T) {
    int lane = threadIdx.x & 63, wv = threadIdx.x >> 6;
    int p = blockIdx.x * 4 + wv;          // table-major: p in [0, 26*8192)
    int t = p >> 13;
    int b = p & 8191;
    const int* ip = idx + (size_t)t * 81920 + b * 10;
    const float* tb = tab + (size_t)t * 100000 * 128;
    float ax = 0.f, ay = 0.f;
    #pragma unroll
    for (int j = 0; j < 10; j++) {
        int r = ip[j];
        float2 v = ((const float2*)(tb + (size_t)r * 128))[lane];
        ax += v.x; ay += v.y;
    }
    __hip_bfloat162 o;
    o.x = __float2bfloat16(ax);
    o.y = __float2bfloat16(ay);
    ((__hip_bfloat162*)(T + (size_t)b * TROW + (1 + t) * 128))[lane] = o;
}

// ---------------- GEMM: C = relu(A @ W^T + bias), TM x TN tile, 4 waves ----------------
template<int TM, int TN, int WM, int WN>
__global__ __launch_bounds__(256) void gemm_t(const __hip_bfloat16* __restrict__ A,
                                              const __hip_bfloat16* __restrict__ W,
                                              const float* __restrict__ bias,
                                              __hip_bfloat16* __restrict__ C,
                                              int M, int N, int K, int ldc) {
    constexpr int ROWS = TM + TN;
    constexpr int CH = ROWS * 4 / 256;
    constexpr int MI = TM / WM / 16;
    constexpr int NI = TN / WN / 16;
    __shared__ __align__(16) __hip_bfloat16 ABs[ROWS * 32];

    const int tid = threadIdx.x;
    const int lane = tid & 63, wave = tid >> 6;
    const int wmI = wave / WN, wnI = wave % WN;
    const int m0 = blockIdx.y * TM, n0 = blockIdx.x * TN;

    const __hip_bfloat16* gp[CH];
    #pragma unroll
    for (int c = 0; c < CH; c++) {
        int gid = c * 256 + tid;
        int row = gid >> 2, col = (gid & 3) * 8;
        gp[c] = (row < TM ? A + (size_t)(m0 + row) * K
                          : W + (size_t)(n0 + row - TM) * K) + col;
    }

    f32x4 acc[MI][NI] = {};
    const int fr = lane & 15, fkb = (lane >> 4) * 8;

    for (int k0 = 0; k0 < K; k0 += 32) {
        __syncthreads();
        #pragma unroll
        for (int c = 0; c < CH; c++)
            gld_lds16(gp[c] + k0, &ABs[(c * 256 + wave * 64) * 8]);
        asm volatile("s_waitcnt vmcnt(0)" ::: "memory");
        __syncthreads();
        bf16x8 a[MI], b[NI];
        #pragma unroll
        for (int i = 0; i < MI; i++)
            a[i] = *(const bf16x8*)&ABs[(wmI * (TM / WM) + i * 16 + fr) * 32 + fkb];
        #pragma unroll
        for (int j = 0; j < NI; j++)
            b[j] = *(const bf16x8*)&ABs[(TM + wnI * (TN / WN) + j * 16 + fr) * 32 + fkb];
        #pragma unroll
        for (int i = 0; i < MI; i++)
            #pragma unroll
            for (int j = 0; j < NI; j++)
                acc[i][j] = __builtin_amdgcn_mfma_f32_16x16x32_bf16(a[i], b[j], acc[i][j], 0, 0, 0);
    }

    const int fq = lane >> 4;
    #pragma unroll
    for (int i = 0; i < MI; i++) {
        #pragma unroll
        for (int j = 0; j < NI; j++) {
            int n = n0 + wnI * (TN / WN) + j * 16 + fr;
            float bv = bias[n];
            #pragma unroll
            for (int r = 0; r < 4; r++) {
                int m = m0 + wmI * (TM / WM) + i * 16 + fq * 4 + r;
                C[(size_t)m * ldc + n] = __float2bfloat16(fmaxf(acc[i][j][r] + bv, 0.f));
            }
        }
    }
}

// ---------------- interaction (LDS-free): 4 samples/block, fragments direct from Tbuf ----------------
// Rows >= 27 of the 32x32 Gram operand read out-of-sample bytes; by matrix-row independence
// they only affect output rows/cols >= 27, which are never stored.
__global__ __launch_bounds__(256) void k_int(const __hip_bfloat16* __restrict__ T,
                                             __hip_bfloat16* __restrict__ z) {
    int lane = threadIdx.x & 63, wave = threadIdx.x >> 6;
    int b = blockIdx.x * 4 + wave;
    const __hip_bfloat16* Tb = T + (size_t)b * TROW;

    const int fr = lane & 15, fkb = (lane >> 4) * 8;
    bf16x8 fr2[2][4];
    #pragma unroll
    for (int mi = 0; mi < 2; mi++)
        #pragma unroll
        for (int kt = 0; kt < 4; kt++)
            fr2[mi][kt] = *(const bf16x8*)&Tb[(mi * 16 + fr) * 128 + kt * 32 + fkb];

    f32x4 acc[2][2] = {};
    #pragma unroll
    for (int kt = 0; kt < 4; kt++)
        #pragma unroll
        for (int mi = 0; mi < 2; mi++)
            #pragma unroll
            for (int ni = 0; ni < 2; ni++)
                acc[mi][ni] = __builtin_amdgcn_mfma_f32_16x16x32_bf16(fr2[mi][kt], fr2[ni][kt], acc[mi][ni], 0, 0, 0);

    __hip_bfloat16* zb = z + (size_t)b * 512;
    ((unsigned*)zb)[lane] = ((const unsigned*)Tb)[lane];       // copy x row (128 bf16)
    if (lane < 33) zb[479 + lane] = __float2bfloat16(0.f);     // pad cols 479..511
    const int fq = lane >> 4;
    #pragma unroll
    for (int mi = 0; mi < 2; mi++)
        #pragma unroll
        for (int ni = 0; ni < 2; ni++)
            #pragma unroll
            for (int r = 0; r < 4; r++) {
                int m = mi * 16 + fq * 4 + r;
                int n = ni * 16 + fr;
                if (m < 27 && n < 27 && m < n) {
                    int p = m * 26 - (m * (m - 1)) / 2 + (n - m - 1);
                    zb[128 + p] = __float2bfloat16(acc[mi][ni][r]);
                }
            }
}

// ---------------- final layer: dot(h[256], w) + b -> sigmoid ----------------
__global__ __launch_bounds__(256) void final_kernel(const __hip_bfloat16* __restrict__ h,
                                                    const float* __restrict__ w,
                                                    const float* __restrict__ bias,
                                                    float* __restrict__ out) {
    int lane = threadIdx.x & 63, wv = threadIdx.x >> 6;
    int s = blockIdx.x * 4 + wv;
    const __hip_bfloat16* hp = h + (size_t)s * 256;
    float sum = 0.f;
    #pragma unroll
    for (int i = 0; i < 4; i++) {
        int k = i * 64 + lane;
        sum += __bfloat162float(hp[k]) * w[k];
    }
    #pragma unroll
    for (int off = 32; off; off >>= 1) sum += __shfl_down(sum, off, 64);
    if (lane == 0) out[s] = 1.f / (1.f + expf(-(sum + bias[0])));
}

extern "C" void kernel_launch(void* const* d_in, const int* in_sizes, int n_in,
                              void* d_out, int out_size, void* d_ws, size_t ws_size,
                              hipStream_t stream) {
    const float* dense_x = (const float*)d_in[0];
    const int* sidx      = (const int*)d_in[1];
    const float* emb     = (const float*)d_in[2];
    const float* bw0 = (const float*)d_in[3];  const float* bb0 = (const float*)d_in[4];
    const float* bw1 = (const float*)d_in[5];  const float* bb1 = (const float*)d_in[6];
    const float* bw2 = (const float*)d_in[7];  const float* bb2 = (const float*)d_in[8];
    const float* tw0 = (const float*)d_in[9];  const float* tb0 = (const float*)d_in[10];
    const float* tw1 = (const float*)d_in[11]; const float* tb1 = (const float*)d_in[12];
    const float* tw2 = (const float*)d_in[13]; const float* tb2 = (const float*)d_in[14];
    const float* tw3 = (const float*)d_in[15]; const float* tb3 = (const float*)d_in[16];
    const float* tw4 = (const float*)d_in[17]; const float* tb4 = (const float*)d_in[18];
    float* out = (float*)d_out;

    char* ws = (char*)d_ws;
    size_t off = 0;
    auto alloc = [&](size_t bytes) {
        off = (off + 255) & ~(size_t)255;
        void* p = ws + off;
        off += bytes;
        return p;
    };
    __hip_bfloat16* Wb1 = (__hip_bfloat16*)alloc((size_t)256 * 512 * 2);
    __hip_bfloat16* Wb2 = (__hip_bfloat16*)alloc((size_t)128 * 256 * 2);
    __hip_bfloat16* Wt0 = (__hip_bfloat16*)alloc((size_t)1024 * 512 * 2);
    __hip_bfloat16* Wt1 = (__hip_bfloat16*)alloc((size_t)1024 * 1024 * 2);
    __hip_bfloat16* Wt2 = (__hip_bfloat16*)alloc((size_t)512 * 1024 * 2);
    __hip_bfloat16* Wt3 = (__hip_bfloat16*)alloc((size_t)256 * 512 * 2);
    __hip_bfloat16* bufA = (__hip_bfloat16*)alloc((size_t)B_SZ * 512 * 2);
    __hip_bfloat16* bufB = (__hip_bfloat16*)alloc((size_t)B_SZ * 256 * 2);
    __hip_bfloat16* Tbuf = (__hip_bfloat16*)alloc((size_t)B_SZ * TROW * 2);
    __hip_bfloat16* zbuf = (__hip_bfloat16*)alloc((size_t)B_SZ * 512 * 2);
    __hip_bfloat16* h0   = (__hip_bfloat16*)alloc((size_t)B_SZ * 1024 * 2);
    __hip_bfloat16* h1   = (__hip_bfloat16*)alloc((size_t)B_SZ * 1024 * 2);
    __hip_bfloat16* h2   = (__hip_bfloat16*)alloc((size_t)B_SZ * 512 * 2);
    __hip_bfloat16* h3   = (__hip_bfloat16*)alloc((size_t)B_SZ * 256 * 2);

    CvtJobs J;
    auto setJob = [&](int i, const float* in, __hip_bfloat16* o, int N, int K, int Kp) {
        J.j[i] = {in, o, N, K, Kp};
    };
    setJob(0, bw1, Wb1, 256, 512, 512);
    setJob(1, bw2, Wb2, 128, 256, 256);
    setJob(2, tw0, Wt0, 1024, 479, 512);
    setJob(3, tw1, Wt1, 1024, 1024, 1024);
    setJob(4, tw2, Wt2, 512, 1024, 1024);
    setJob(5, tw3, Wt3, 256, 512, 512);
    J.start[0] = 0;
    for (int i = 0; i < 6; i++) J.start[i + 1] = J.start[i] + J.j[i].N * J.j[i].Kp;
    const int cvtB = (J.start[6] / 8 + 255) / 256;

    // L1: weight cvt || bot0 (fp32 direct, K=13)
    k_pre<<<cvtB + B_SZ / 4, 256, 0, stream>>>(J, cvtB, dense_x, bw0, bb0, bufA);

    // L2: embeddings, isolated & lean (table-major for L3 reuse)
    emb_kernel<<<26 * B_SZ / 4, 256, 0, stream>>>(sidx, emb, Tbuf);

    // L3-L4: rest of bottom MLP
    gemm_t<128, 64, 2, 2><<<dim3(256 / 64, B_SZ / 128), 256, 0, stream>>>(bufA, Wb1, bb1, bufB, B_SZ, 256, 512, 256);
    gemm_t< 64, 64, 2, 2><<<dim3(128 / 64, B_SZ /  64), 256, 0, stream>>>(bufB, Wb2, bb2, Tbuf, B_SZ, 128, 256, TROW);

    // L5: interaction -> z (B x 512, padded)
    k_int<<<B_SZ / 4, 256, 0, stream>>>(Tbuf, zbuf);

    // L6-L9: top MLP (128x64 tiles -> 4 blocks/CU on the big layers)
    gemm_t<128, 64, 2, 2><<<dim3(1024 / 64, B_SZ / 128), 256, 0, stream>>>(zbuf, Wt0, tb0, h0, B_SZ, 1024, 512, 1024);
    gemm_t<128, 64, 2, 2><<<dim3(1024 / 64, B_SZ / 128), 256, 0, stream>>>(h0, Wt1, tb1, h1, B_SZ, 1024, 1024, 1024);
    gemm_t<128, 64, 2, 2><<<dim3( 512 / 64, B_SZ / 128), 256, 0, stream>>>(h1, Wt2, tb2, h2, B_SZ, 512, 1024, 512);
    gemm_t<128, 64, 2, 2><<<dim3( 256 / 64, B_SZ / 128), 256, 0, stream>>>(h2, Wt3, tb3, h3, B_SZ, 256, 512, 256);

    // L10: final dot + sigmoid
    final_kernel<<<B_SZ / 4, 256, 0, stream>>>(h3, tw4, tb4, out);
}